// Round 6
// baseline (22197.525 us; speedup 1.0000x reference)
//
#include <hip/hip_runtime.h>

// R6: pure fp32-VALU implementation, FP32 OUTPUT (the R1-R5 bug: output
// buffer is float32 per the reference's output dtype; bf16 halfwords were
// being glued into garbage floats by the validator).
//
// 256 blocks x 512 threads. Block owns 32 batch rows. Thread owns
// h-column hc = tid&127 and row-group rg = tid>>7 (8 rows), computing all
// 4 gate preactivations for its (rows, hc) via fp32 dots; weights read
// from global (L2-resident, ~1.3MB total).

#define DEV static __device__ __forceinline__

DEV float sigm(float v) { return 1.0f / (1.0f + __expf(-v)); }
DEV float tanh_(float v) {
  float e = __expf(-2.0f * fabsf(v));
  float r = (1.0f - e) / (1.0f + e);
  return v < 0.0f ? -r : r;
}
DEV float cellf(float gi, float gf, float gg, float go, float& c) {
  float i = sigm(gi), f = sigm(gf), g2 = tanh_(gg), o = sigm(go);
  c = f * c + i * g2;
  return o * tanh_(c);
}

__global__ __launch_bounds__(512, 2) void valu_kernel(
    const float* __restrict__ x,
    const float* __restrict__ eWih0, const float* __restrict__ eWhh0,
    const float* __restrict__ ebih0, const float* __restrict__ ebhh0,
    const float* __restrict__ eWih1, const float* __restrict__ eWhh1,
    const float* __restrict__ ebih1, const float* __restrict__ ebhh1,
    const float* __restrict__ dWih0, const float* __restrict__ dWhh0,
    const float* __restrict__ dbih0, const float* __restrict__ dbhh0,
    const float* __restrict__ dWih1, const float* __restrict__ dWhh1,
    const float* __restrict__ dbih1, const float* __restrict__ dbhh1,
    const float* __restrict__ fcW, const float* __restrict__ fcb,
    float* __restrict__ out) {
  __shared__ float h0[32][128], h1[32][128], xt[32][16], inp[32][2];

  const int tid = threadIdx.x;
  const int hc = tid & 127, rg = tid >> 7;
  const int row0 = blockIdx.x * 32;

  float b0[4], b1[4];
#pragma unroll
  for (int g = 0; g < 4; ++g) {
    b0[g] = ebih0[g * 128 + hc] + ebhh0[g * 128 + hc];
    b1[g] = ebih1[g * 128 + hc] + ebhh1[g * 128 + hc];
  }
  float c0[8], c1[8];
#pragma unroll
  for (int r = 0; r < 8; ++r) { c0[r] = 0.f; c1[r] = 0.f; }
  for (int i = tid; i < 4096; i += 512) {
    (&h0[0][0])[i] = 0.f;
    (&h1[0][0])[i] = 0.f;
  }
  __syncthreads();

  // ================= encoder (T=100) =================
  for (int t = 0; t < 100; ++t) {
    { int r = tid >> 4, f = tid & 15;
      xt[r][f] = x[(long long)(row0 + r) * 1600 + t * 16 + f]; }
    __syncthreads();

    float acc[4][8];
#pragma unroll
    for (int g = 0; g < 4; ++g)
#pragma unroll
      for (int r = 0; r < 8; ++r) acc[g][r] = b0[g];

    // x_t @ eWih0^T  (K=16)
    for (int k = 0; k < 16; k += 4) {
      float4 xv[8];
#pragma unroll
      for (int r = 0; r < 8; ++r) xv[r] = *(const float4*)(&xt[rg * 8 + r][k]);
#pragma unroll
      for (int g = 0; g < 4; ++g) {
        float4 wv = *(const float4*)(eWih0 + (g * 128 + hc) * 16 + k);
#pragma unroll
        for (int r = 0; r < 8; ++r)
          acc[g][r] += xv[r].x * wv.x + xv[r].y * wv.y + xv[r].z * wv.z + xv[r].w * wv.w;
      }
    }
    // h0 @ eWhh0^T  (K=128)
    for (int k = 0; k < 128; k += 4) {
      float4 hv[8];
#pragma unroll
      for (int r = 0; r < 8; ++r) hv[r] = *(const float4*)(&h0[rg * 8 + r][k]);
#pragma unroll
      for (int g = 0; g < 4; ++g) {
        float4 wv = *(const float4*)(eWhh0 + (g * 128 + hc) * 128 + k);
#pragma unroll
        for (int r = 0; r < 8; ++r)
          acc[g][r] += hv[r].x * wv.x + hv[r].y * wv.y + hv[r].z * wv.z + hv[r].w * wv.w;
      }
    }
    float hnew[8];
#pragma unroll
    for (int r = 0; r < 8; ++r)
      hnew[r] = cellf(acc[0][r], acc[1][r], acc[2][r], acc[3][r], c0[r]);
    __syncthreads();
#pragma unroll
    for (int r = 0; r < 8; ++r) h0[rg * 8 + r][hc] = hnew[r];
    __syncthreads();

    // ---- layer 1: h0new @ eWih1^T + h1 @ eWhh1^T
#pragma unroll
    for (int g = 0; g < 4; ++g)
#pragma unroll
      for (int r = 0; r < 8; ++r) acc[g][r] = b1[g];
    for (int k = 0; k < 128; k += 4) {
      float4 hv[8];
#pragma unroll
      for (int r = 0; r < 8; ++r) hv[r] = *(const float4*)(&h0[rg * 8 + r][k]);
#pragma unroll
      for (int g = 0; g < 4; ++g) {
        float4 wv = *(const float4*)(eWih1 + (g * 128 + hc) * 128 + k);
#pragma unroll
        for (int r = 0; r < 8; ++r)
          acc[g][r] += hv[r].x * wv.x + hv[r].y * wv.y + hv[r].z * wv.z + hv[r].w * wv.w;
      }
    }
    for (int k = 0; k < 128; k += 4) {
      float4 hv[8];
#pragma unroll
      for (int r = 0; r < 8; ++r) hv[r] = *(const float4*)(&h1[rg * 8 + r][k]);
#pragma unroll
      for (int g = 0; g < 4; ++g) {
        float4 wv = *(const float4*)(eWhh1 + (g * 128 + hc) * 128 + k);
#pragma unroll
        for (int r = 0; r < 8; ++r)
          acc[g][r] += hv[r].x * wv.x + hv[r].y * wv.y + hv[r].z * wv.z + hv[r].w * wv.w;
      }
    }
#pragma unroll
    for (int r = 0; r < 8; ++r)
      hnew[r] = cellf(acc[0][r], acc[1][r], acc[2][r], acc[3][r], c1[r]);
    __syncthreads();
#pragma unroll
    for (int r = 0; r < 8; ++r) h1[rg * 8 + r][hc] = hnew[r];
    __syncthreads();
  }

  // ================= decoder (TGT=60) =================
  if (tid < 64) {
    int r = tid >> 1, o = tid & 1;
    inp[r][o] = x[(long long)(row0 + r) * 1600 + 1584 + o];  // x[:, 99, :2]
  }
  float dwx[4][2];
#pragma unroll
  for (int g = 0; g < 4; ++g) {
    b0[g] = dbih0[g * 128 + hc] + dbhh0[g * 128 + hc];
    b1[g] = dbih1[g * 128 + hc] + dbhh1[g * 128 + hc];
    dwx[g][0] = dWih0[(g * 128 + hc) * 2 + 0];
    dwx[g][1] = dWih0[(g * 128 + hc) * 2 + 1];
  }
  __syncthreads();

  for (int t = 0; t < 60; ++t) {
    float acc[4][8];
#pragma unroll
    for (int g = 0; g < 4; ++g)
#pragma unroll
      for (int r = 0; r < 8; ++r)
        acc[g][r] = b0[g] + inp[rg * 8 + r][0] * dwx[g][0] + inp[rg * 8 + r][1] * dwx[g][1];
    for (int k = 0; k < 128; k += 4) {
      float4 hv[8];
#pragma unroll
      for (int r = 0; r < 8; ++r) hv[r] = *(const float4*)(&h0[rg * 8 + r][k]);
#pragma unroll
      for (int g = 0; g < 4; ++g) {
        float4 wv = *(const float4*)(dWhh0 + (g * 128 + hc) * 128 + k);
#pragma unroll
        for (int r = 0; r < 8; ++r)
          acc[g][r] += hv[r].x * wv.x + hv[r].y * wv.y + hv[r].z * wv.z + hv[r].w * wv.w;
      }
    }
    float hnew[8];
#pragma unroll
    for (int r = 0; r < 8; ++r)
      hnew[r] = cellf(acc[0][r], acc[1][r], acc[2][r], acc[3][r], c0[r]);
    __syncthreads();
#pragma unroll
    for (int r = 0; r < 8; ++r) h0[rg * 8 + r][hc] = hnew[r];
    __syncthreads();

    // ---- layer 1
#pragma unroll
    for (int g = 0; g < 4; ++g)
#pragma unroll
      for (int r = 0; r < 8; ++r) acc[g][r] = b1[g];
    for (int k = 0; k < 128; k += 4) {
      float4 hv[8];
#pragma unroll
      for (int r = 0; r < 8; ++r) hv[r] = *(const float4*)(&h0[rg * 8 + r][k]);
#pragma unroll
      for (int g = 0; g < 4; ++g) {
        float4 wv = *(const float4*)(dWih1 + (g * 128 + hc) * 128 + k);
#pragma unroll
        for (int r = 0; r < 8; ++r)
          acc[g][r] += hv[r].x * wv.x + hv[r].y * wv.y + hv[r].z * wv.z + hv[r].w * wv.w;
      }
    }
    for (int k = 0; k < 128; k += 4) {
      float4 hv[8];
#pragma unroll
      for (int r = 0; r < 8; ++r) hv[r] = *(const float4*)(&h1[rg * 8 + r][k]);
#pragma unroll
      for (int g = 0; g < 4; ++g) {
        float4 wv = *(const float4*)(dWhh1 + (g * 128 + hc) * 128 + k);
#pragma unroll
        for (int r = 0; r < 8; ++r)
          acc[g][r] += hv[r].x * wv.x + hv[r].y * wv.y + hv[r].z * wv.z + hv[r].w * wv.w;
      }
    }
#pragma unroll
    for (int r = 0; r < 8; ++r)
      hnew[r] = cellf(acc[0][r], acc[1][r], acc[2][r], acc[3][r], c1[r]);
    __syncthreads();
#pragma unroll
    for (int r = 0; r < 8; ++r) h1[rg * 8 + r][hc] = hnew[r];
    __syncthreads();

    // ---- FC head + feedback (fp32 output store)
    if (tid < 64) {
      int r = tid >> 1, o = tid & 1;
      float s = fcb[o];
      for (int k = 0; k < 128; k += 4) {
        float4 wv = *(const float4*)(fcW + o * 128 + k);
        float4 hv = *(const float4*)(&h1[r][k]);
        s += hv.x * wv.x + hv.y * wv.y + hv.z * wv.z + hv.w * wv.w;
      }
      inp[r][o] = s;
      out[((long long)(row0 + r) * 60 + t) * 2 + o] = s;
    }
    __syncthreads();
  }
}

extern "C" void kernel_launch(void* const* d_in, const int* in_sizes, int n_in,
                              void* d_out, int out_size, void* d_ws, size_t ws_size,
                              hipStream_t stream) {
  (void)in_sizes; (void)n_in; (void)out_size; (void)d_ws; (void)ws_size;
  const float* x      = (const float*)d_in[0];
  // d_in[1] = target_len (60), hardcoded
  const float* eWih0  = (const float*)d_in[2];
  const float* eWhh0  = (const float*)d_in[3];
  const float* ebih0  = (const float*)d_in[4];
  const float* ebhh0  = (const float*)d_in[5];
  const float* eWih1  = (const float*)d_in[6];
  const float* eWhh1  = (const float*)d_in[7];
  const float* ebih1  = (const float*)d_in[8];
  const float* ebhh1  = (const float*)d_in[9];
  const float* dWih0  = (const float*)d_in[10];
  const float* dWhh0  = (const float*)d_in[11];
  const float* dbih0  = (const float*)d_in[12];
  const float* dbhh0  = (const float*)d_in[13];
  const float* dWih1  = (const float*)d_in[14];
  const float* dWhh1  = (const float*)d_in[15];
  const float* dbih1  = (const float*)d_in[16];
  const float* dbhh1  = (const float*)d_in[17];
  const float* fcW    = (const float*)d_in[18];
  const float* fcb    = (const float*)d_in[19];
  float* out          = (float*)d_out;

  valu_kernel<<<256, 512, 0, stream>>>(
      x, eWih0, eWhh0, ebih0, ebhh0, eWih1, eWhh1, ebih1, ebhh1,
      dWih0, dWhh0, dbih0, dbhh0, dWih1, dWhh1, dbih1, dbhh1,
      fcW, fcb, out);
}

// Round 7
// 2228.518 us; speedup vs baseline: 9.9607x; 9.9607x over previous
//
#include <hip/hip_runtime.h>
#include <hip/hip_bf16.h>

// R7: fused fp16-MFMA kernel (R3 structure, validated mappings) with FP32
// OUTPUT stores (the R1-R5 bug fix). Doubles as precision-gain calibration:
// absmax / ~1e-4 estimates the recurrence noise gain G.
//
// 256 blocks x 512 threads (8 waves). Block owns 32 batch rows end-to-end.
// Wave w owns H-columns [16w,16w+16). MFMA 16x16x32 f16. LDS 118016B:
//   wL 96KB: W_hh0 gates i,f,g swizzled fp16; gate o + layer-1 W in regs.
// c stays fp32 in registers; decoder feedback inp stays fp32.

using s16x8 = __attribute__((ext_vector_type(8))) short;
using h16x8 = __attribute__((ext_vector_type(8))) _Float16;
using f32x4 = __attribute__((ext_vector_type(4))) float;

#define DEV static __device__ __forceinline__

DEV unsigned short f2h(float f) {
  _Float16 h = (_Float16)f;  // RNE
  return __builtin_bit_cast(unsigned short, h);
}
DEV float h2f(short h) {
  return (float)__builtin_bit_cast(_Float16, (unsigned short)h);
}
DEV float sigm(float v) { return 1.0f / (1.0f + __expf(-v)); }
DEV float tanh_(float v) {
  float e = __expf(-2.0f * fabsf(v));
  float r = (1.0f - e) / (1.0f + e);
  return v < 0.0f ? -r : r;
}
DEV f32x4 mf(s16x8 a, s16x8 b, f32x4 c) {
  return __builtin_amdgcn_mfma_f32_16x16x32_f16(
      __builtin_bit_cast(h16x8, a), __builtin_bit_cast(h16x8, b), c, 0, 0, 0);
}
DEV f32x4 splat4(float v) { f32x4 r = {v, v, v, v}; return r; }

// byte offset into a [rows][128] fp16 buffer; 16 slots of 8 fp16 per row,
// slot XOR-swizzled by row&15 -> conflict-free ds_read_b128 down columns.
DEV int swz(int row, int slot) { return row * 256 + (((slot ^ row) & 15) << 4); }

// stage one row of a [*][128] fp32 weight matrix -> swizzled fp16 LDS row
DEV void stageWrow(const float* __restrict__ W, char* lds, int r) {
  const float4* p = (const float4*)(W + r * 128);
#pragma unroll
  for (int s = 0; s < 16; ++s) {
    float4 a = p[2 * s], b = p[2 * s + 1];
    s16x8 v;
    v[0] = (short)f2h(a.x); v[1] = (short)f2h(a.y);
    v[2] = (short)f2h(a.z); v[3] = (short)f2h(a.w);
    v[4] = (short)f2h(b.x); v[5] = (short)f2h(b.y);
    v[6] = (short)f2h(b.z); v[7] = (short)f2h(b.w);
    *(s16x8*)(lds + swz(r, s)) = v;
  }
}

// register B-fragment from a [512][128] fp32 matrix: col fixed, k = s*32+hi*8+j
DEV s16x8 ldWfrag128(const float* __restrict__ W, int col, int s, int hi) {
  const float4* p = (const float4*)(W + col * 128 + s * 32 + hi * 8);
  float4 a = p[0], b = p[1];
  s16x8 v;
  v[0] = (short)f2h(a.x); v[1] = (short)f2h(a.y);
  v[2] = (short)f2h(a.z); v[3] = (short)f2h(a.w);
  v[4] = (short)f2h(b.x); v[5] = (short)f2h(b.y);
  v[6] = (short)f2h(b.z); v[7] = (short)f2h(b.w);
  return v;
}
// K=16 matrix (x-projection), zero-padded to K=32: lanes hi>=2 hold zeros
DEV s16x8 ldWfrag16(const float* __restrict__ W, int col, int hi) {
  s16x8 v;
#pragma unroll
  for (int j = 0; j < 8; ++j) v[j] = 0;
  if (hi < 2) {
    const float4* p = (const float4*)(W + col * 16 + hi * 8);
    float4 a = p[0], b = p[1];
    v[0] = (short)f2h(a.x); v[1] = (short)f2h(a.y);
    v[2] = (short)f2h(a.z); v[3] = (short)f2h(a.w);
    v[4] = (short)f2h(b.x); v[5] = (short)f2h(b.y);
    v[6] = (short)f2h(b.z); v[7] = (short)f2h(b.w);
  }
  return v;
}

// A fragment from a swizzled [32][128] fp16 h-buffer
DEV s16x8 ldA(const char* buf, int rt, int ks, int lo, int hi) {
  return *(const s16x8*)(buf + swz(rt * 16 + lo, ks * 4 + hi));
}
// B fragment from the LDS-resident weight matrix
DEV s16x8 ldB(const char* wlds, int colbase, int ks, int lo, int hi) {
  return *(const s16x8*)(wlds + swz(colbase + lo, ks * 4 + hi));
}
// scatter one fp16 h value into the swizzled h-buffer
DEV void storeH(char* buf, int row, int col, unsigned short v) {
  int addr = row * 256 + ((((col >> 3) ^ row) & 15) << 4) + (col & 7) * 2;
  *(unsigned short*)(buf + addr) = v;
}
// LSTM pointwise: gates (i,f,g,o) -> update c, return fp16(h)
DEV unsigned short cellup(float gi, float gf, float gg, float go, float& c) {
  float i = sigm(gi), f = sigm(gf), g2 = tanh_(gg), o = sigm(go);
  c = f * c + i * g2;
  return f2h(o * tanh_(c));
}

#define SMEM_BYTES 118016

__global__ __launch_bounds__(512, 2) void fused_kernel(
    const float* __restrict__ x,
    const float* __restrict__ eWih0, const float* __restrict__ eWhh0,
    const float* __restrict__ ebih0, const float* __restrict__ ebhh0,
    const float* __restrict__ eWih1, const float* __restrict__ eWhh1,
    const float* __restrict__ ebih1, const float* __restrict__ ebhh1,
    const float* __restrict__ dWih0, const float* __restrict__ dWhh0,
    const float* __restrict__ dbih0, const float* __restrict__ dbhh0,
    const float* __restrict__ dWih1, const float* __restrict__ dWhh1,
    const float* __restrict__ dbih1, const float* __restrict__ dbhh1,
    const float* __restrict__ fcW, const float* __restrict__ fcb,
    float* __restrict__ out) {
  extern __shared__ char smem[];
  char* wL   = smem;                       // 98304: W_hh0 gates 0..2 swizzled
  char* h0L  = smem + 98304;               // 8192
  char* h1L  = smem + 106496;              // 8192
  char* xL   = smem + 114688;              // 2560 (32 rows * 80B, K pad to 32)
  float* inpL = (float*)(smem + 117248);   // 256: 32x2 fp32 decoder feedback
  char* fcwL = smem + 117504;              // 512: 2x128 fp16

  const int tid = threadIdx.x;
  const int w = tid >> 6, l = tid & 63, lo = l & 15, hi = l >> 4;
  const int row0 = blockIdx.x * 32;
  const int colb = w * 16;

  // ================= encoder phase =================
  if (tid < 384) stageWrow(eWhh0, wL, tid);
  {  // zero h0,h1 and x buffer (incl. K-padding)
    int4 z = make_int4(0, 0, 0, 0);
    int4* p = (int4*)h0L;
    for (int i = tid; i < 1024; i += 512) p[i] = z;
    int4* q = (int4*)xL;
    for (int i = tid; i < 160; i += 512) q[i] = z;
  }

  float b0[4], b1[4];
  s16x8 wg3[4], wx0[4], wi1[4][4], wh1[4][4];
#pragma unroll
  for (int g = 0; g < 4; ++g) {
    int col = g * 128 + colb + lo;
    b0[g] = ebih0[col] + ebhh0[col];
    b1[g] = ebih1[col] + ebhh1[col];
    wx0[g] = ldWfrag16(eWih0, col, hi);
#pragma unroll
    for (int s = 0; s < 4; ++s) {
      wi1[g][s] = ldWfrag128(eWih1, col, s, hi);
      wh1[g][s] = ldWfrag128(eWhh1, col, s, hi);
    }
  }
#pragma unroll
  for (int s = 0; s < 4; ++s) wg3[s] = ldWfrag128(eWhh0, 384 + colb + lo, s, hi);

  float c0s[2][4], c1s[2][4];
#pragma unroll
  for (int rt = 0; rt < 2; ++rt)
#pragma unroll
    for (int r = 0; r < 4; ++r) { c0s[rt][r] = 0.f; c1s[rt][r] = 0.f; }
  __syncthreads();

  for (int t = 0; t < 100; ++t) {
    {  // stage x_t (fp16, rows 0..31, features 0..15)
      int r = tid >> 4, f = tid & 15;
      float xv = x[(long long)(row0 + r) * 1600 + t * 16 + f];
      *(unsigned short*)(xL + r * 80 + f * 2) = f2h(xv);
    }
    __syncthreads();

    // ---- layer 0: g = x@Wih0^T + h0@Whh0^T + b0
    f32x4 acc[2][4];
#pragma unroll
    for (int g = 0; g < 4; ++g) { acc[0][g] = splat4(b0[g]); acc[1][g] = splat4(b0[g]); }
    {
      s16x8 a0 = *(const s16x8*)(xL + lo * 80 + hi * 16);
      s16x8 a1 = *(const s16x8*)(xL + (16 + lo) * 80 + hi * 16);
#pragma unroll
      for (int g = 0; g < 4; ++g) {
        acc[0][g] = mf(a0, wx0[g], acc[0][g]);
        acc[1][g] = mf(a1, wx0[g], acc[1][g]);
      }
    }
#pragma unroll
    for (int ks = 0; ks < 4; ++ks) {
      s16x8 a0 = ldA(h0L, 0, ks, lo, hi), a1 = ldA(h0L, 1, ks, lo, hi);
#pragma unroll
      for (int g = 0; g < 3; ++g) {
        s16x8 bb = ldB(wL, g * 128 + colb, ks, lo, hi);
        acc[0][g] = mf(a0, bb, acc[0][g]);
        acc[1][g] = mf(a1, bb, acc[1][g]);
      }
      acc[0][3] = mf(a0, wg3[ks], acc[0][3]);
      acc[1][3] = mf(a1, wg3[ks], acc[1][3]);
    }
    unsigned short hb[2][4];
#pragma unroll
    for (int rt = 0; rt < 2; ++rt)
#pragma unroll
      for (int r = 0; r < 4; ++r)
        hb[rt][r] = cellup(acc[rt][0][r], acc[rt][1][r], acc[rt][2][r], acc[rt][3][r], c0s[rt][r]);
    __syncthreads();  // everyone done reading old h0
#pragma unroll
    for (int rt = 0; rt < 2; ++rt)
#pragma unroll
      for (int r = 0; r < 4; ++r)
        storeH(h0L, rt * 16 + hi * 4 + r, colb + lo, hb[rt][r]);
    __syncthreads();

    // ---- layer 1: g = h0new@Wih1^T + h1@Whh1^T + b1
#pragma unroll
    for (int g = 0; g < 4; ++g) { acc[0][g] = splat4(b1[g]); acc[1][g] = splat4(b1[g]); }
#pragma unroll
    for (int s = 0; s < 8; ++s) {
      const char* src = (s < 4) ? h0L : h1L;
      int ks = s & 3;
      s16x8 a0 = ldA(src, 0, ks, lo, hi), a1 = ldA(src, 1, ks, lo, hi);
#pragma unroll
      for (int g = 0; g < 4; ++g) {
        s16x8 bb = (s < 4) ? wi1[g][ks] : wh1[g][ks];
        acc[0][g] = mf(a0, bb, acc[0][g]);
        acc[1][g] = mf(a1, bb, acc[1][g]);
      }
    }
#pragma unroll
    for (int rt = 0; rt < 2; ++rt)
#pragma unroll
      for (int r = 0; r < 4; ++r)
        hb[rt][r] = cellup(acc[rt][0][r], acc[rt][1][r], acc[rt][2][r], acc[rt][3][r], c1s[rt][r]);
    __syncthreads();
#pragma unroll
    for (int rt = 0; rt < 2; ++rt)
#pragma unroll
      for (int r = 0; r < 4; ++r)
        storeH(h1L, rt * 16 + hi * 4 + r, colb + lo, hb[rt][r]);
    __syncthreads();
  }

  // ================= restage for decoder =================
  // (h0L/h1L and c-registers already hold encoder-final states in place)
  if (tid < 384) stageWrow(dWhh0, wL, tid);
  if (tid < 64) {  // dec_in = x[:, 99, :2] (fp32)
    int r = tid >> 1, o = tid & 1;
    inpL[r * 2 + o] = x[(long long)(row0 + r) * 1600 + 1584 + o];
  }
  if (tid < 256) {
    int o = tid >> 7, k = tid & 127;
    *(unsigned short*)(fcwL + o * 256 + k * 2) = f2h(fcW[o * 128 + k]);
  }
  float dwx[4][2];
#pragma unroll
  for (int g = 0; g < 4; ++g) {
    int col = g * 128 + colb + lo;
    b0[g] = dbih0[col] + dbhh0[col];
    b1[g] = dbih1[col] + dbhh1[col];
    dwx[g][0] = dWih0[col * 2 + 0];
    dwx[g][1] = dWih0[col * 2 + 1];
#pragma unroll
    for (int s = 0; s < 4; ++s) {
      wi1[g][s] = ldWfrag128(dWih1, col, s, hi);
      wh1[g][s] = ldWfrag128(dWhh1, col, s, hi);
    }
  }
#pragma unroll
  for (int s = 0; s < 4; ++s) wg3[s] = ldWfrag128(dWhh0, 384 + colb + lo, s, hi);
  float fb0 = fcb[0], fb1 = fcb[1];
  __syncthreads();

  // ================= decoder phase =================
  for (int t = 0; t < 60; ++t) {
    // ---- layer 0: g = inp@dWih0^T (VALU fp32, K=2) + h0@dWhh0^T + b0
    f32x4 acc[2][4];
#pragma unroll
    for (int rt = 0; rt < 2; ++rt)
#pragma unroll
      for (int r = 0; r < 4; ++r) {
        float2 ip = *(const float2*)(inpL + (rt * 16 + hi * 4 + r) * 2);
#pragma unroll
        for (int g = 0; g < 4; ++g)
          acc[rt][g][r] = b0[g] + ip.x * dwx[g][0] + ip.y * dwx[g][1];
      }
#pragma unroll
    for (int ks = 0; ks < 4; ++ks) {
      s16x8 a0 = ldA(h0L, 0, ks, lo, hi), a1 = ldA(h0L, 1, ks, lo, hi);
#pragma unroll
      for (int g = 0; g < 3; ++g) {
        s16x8 bb = ldB(wL, g * 128 + colb, ks, lo, hi);
        acc[0][g] = mf(a0, bb, acc[0][g]);
        acc[1][g] = mf(a1, bb, acc[1][g]);
      }
      acc[0][3] = mf(a0, wg3[ks], acc[0][3]);
      acc[1][3] = mf(a1, wg3[ks], acc[1][3]);
    }
    unsigned short hb[2][4];
#pragma unroll
    for (int rt = 0; rt < 2; ++rt)
#pragma unroll
      for (int r = 0; r < 4; ++r)
        hb[rt][r] = cellup(acc[rt][0][r], acc[rt][1][r], acc[rt][2][r], acc[rt][3][r], c0s[rt][r]);
    __syncthreads();
#pragma unroll
    for (int rt = 0; rt < 2; ++rt)
#pragma unroll
      for (int r = 0; r < 4; ++r)
        storeH(h0L, rt * 16 + hi * 4 + r, colb + lo, hb[rt][r]);
    __syncthreads();

    // ---- layer 1
#pragma unroll
    for (int g = 0; g < 4; ++g) { acc[0][g] = splat4(b1[g]); acc[1][g] = splat4(b1[g]); }
#pragma unroll
    for (int s = 0; s < 8; ++s) {
      const char* src = (s < 4) ? h0L : h1L;
      int ks = s & 3;
      s16x8 a0 = ldA(src, 0, ks, lo, hi), a1 = ldA(src, 1, ks, lo, hi);
#pragma unroll
      for (int g = 0; g < 4; ++g) {
        s16x8 bb = (s < 4) ? wi1[g][ks] : wh1[g][ks];
        acc[0][g] = mf(a0, bb, acc[0][g]);
        acc[1][g] = mf(a1, bb, acc[1][g]);
      }
    }
#pragma unroll
    for (int rt = 0; rt < 2; ++rt)
#pragma unroll
      for (int r = 0; r < 4; ++r)
        hb[rt][r] = cellup(acc[rt][0][r], acc[rt][1][r], acc[rt][2][r], acc[rt][3][r], c1s[rt][r]);
    __syncthreads();
#pragma unroll
    for (int rt = 0; rt < 2; ++rt)
#pragma unroll
      for (int r = 0; r < 4; ++r)
        storeH(h1L, rt * 16 + hi * 4 + r, colb + lo, hb[rt][r]);
    __syncthreads();

    // ---- FC head + feedback (waves 0,1: lane -> (row, o, k-half))
    if (w < 2) {
      int row = w * 16 + lo;
      int o = hi & 1, kh = hi >> 1;
      float sum = 0.f;
#pragma unroll
      for (int cc = 0; cc < 8; ++cc) {
        s16x8 hv = *(const s16x8*)(h1L + swz(row, kh * 8 + cc));
        s16x8 wv = *(const s16x8*)(fcwL + o * 256 + (kh * 8 + cc) * 16);
#pragma unroll
        for (int j = 0; j < 8; ++j) sum += h2f(hv[j]) * h2f(wv[j]);
      }
      sum += __shfl_xor(sum, 32, 64);
      if (l < 32) {
        float ov = sum + (o ? fb1 : fb0);
        inpL[row * 2 + o] = ov;  // fp32 feedback, matches reference carry
        out[((long long)(row0 + row) * 60 + t) * 2 + o] = ov;  // FP32 store
      }
    }
    __syncthreads();
  }
}

extern "C" void kernel_launch(void* const* d_in, const int* in_sizes, int n_in,
                              void* d_out, int out_size, void* d_ws, size_t ws_size,
                              hipStream_t stream) {
  (void)in_sizes; (void)n_in; (void)out_size; (void)d_ws; (void)ws_size;
  const float* x      = (const float*)d_in[0];
  // d_in[1] = target_len (60), hardcoded
  const float* eWih0  = (const float*)d_in[2];
  const float* eWhh0  = (const float*)d_in[3];
  const float* ebih0  = (const float*)d_in[4];
  const float* ebhh0  = (const float*)d_in[5];
  const float* eWih1  = (const float*)d_in[6];
  const float* eWhh1  = (const float*)d_in[7];
  const float* ebih1  = (const float*)d_in[8];
  const float* ebhh1  = (const float*)d_in[9];
  const float* dWih0  = (const float*)d_in[10];
  const float* dWhh0  = (const float*)d_in[11];
  const float* dbih0  = (const float*)d_in[12];
  const float* dbhh0  = (const float*)d_in[13];
  const float* dWih1  = (const float*)d_in[14];
  const float* dWhh1  = (const float*)d_in[15];
  const float* dbih1  = (const float*)d_in[16];
  const float* dbhh1  = (const float*)d_in[17];
  const float* fcW    = (const float*)d_in[18];
  const float* fcb    = (const float*)d_in[19];
  float* out          = (float*)d_out;

  hipFuncSetAttribute(reinterpret_cast<const void*>(fused_kernel),
                      hipFuncAttributeMaxDynamicSharedMemorySize, SMEM_BYTES);

  fused_kernel<<<256, 512, SMEM_BYTES, stream>>>(
      x, eWih0, eWhh0, ebih0, ebhh0, eWih1, eWhh1, ebih1, ebhh1,
      dWih0, dWhh0, dbih0, dbhh0, dWih1, dWhh1, dbih1, dbhh1,
      fcW, fcb, out);
}